// Round 4
// baseline (149.850 us; speedup 1.0000x reference)
//
#include <hip/hip_runtime.h>
#include <stdint.h>

#define N2 2048
#define NN (2048UL * 2048UL)

typedef __attribute__((ext_vector_type(8))) short short8;
typedef __attribute__((ext_vector_type(8))) unsigned short u16x8;
typedef __attribute__((ext_vector_type(4))) float f32x4;

__device__ __forceinline__ unsigned short f2bf(float f) {
    unsigned int u = __float_as_uint(f);
    u += 0x7FFFu + ((u >> 16) & 1u);   // round-to-nearest-even
    return (unsigned short)(u >> 16);
}
__device__ __forceinline__ float bf2f(unsigned short u) {
    return __uint_as_float((unsigned int)u << 16);
}

__device__ __forceinline__ void gload16(const void* g, void* l) {
    __builtin_amdgcn_global_load_lds(
        (const __attribute__((address_space(1))) unsigned int*)g,
        (__attribute__((address_space(3))) unsigned int*)l, 16, 0, 0);
}

// ---------------------------------------------------------------------------
// combine: HA[c][n][m]  = sum_e s1[c][e] A[e][n][m]   (bf16, row-major)
//          HBt[c][m][n] = sum_e s2[c][e] A[e][n][m]   (bf16, transposed)
//          HB2t[c][m][n]= sum_e s3[c][e] A[e][n][m]   (bf16, transposed)
//          PB2[c][bx][n] = partial row sums of HB2-combine over this m-block
// 64x64 tile, 512 threads, full-occupancy (4 blocks/CU = 2048 thr).
// ---------------------------------------------------------------------------
__global__ __launch_bounds__(512, 4) void combine_kernel(
    const float* __restrict__ A, const float* __restrict__ w01,
    const float* __restrict__ w02, const float* __restrict__ w11,
    unsigned short* __restrict__ HA, unsigned short* __restrict__ HBt,
    unsigned short* __restrict__ HB2t, float* __restrict__ PB2) {
    __shared__ float s[3][2][5];
    __shared__ float tile[2][64][68];   // 34.8 KB
    const int tid = threadIdx.x;
    if (tid < 6) {
        const int wi = tid >> 1, c = tid & 1;
        const float* w = (wi == 0 ? w01 : (wi == 1 ? w02 : w11)) + c * 5;
        float mx = w[0];
        for (int e = 1; e < 5; e++) mx = fmaxf(mx, w[e]);
        float ex[5], sum = 0.f;
        for (int e = 0; e < 5; e++) { ex[e] = expf(w[e] - mx); sum += ex[e]; }
        for (int e = 0; e < 5; e++) s[wi][c][e] = ex[e] / sum;
    }
    __syncthreads();

    const int nr  = tid >> 3;          // 0..63
    const int mc8 = (tid & 7) * 8;     // 0..56
    const size_t gn = (size_t)blockIdx.y * 64 + nr;
    const size_t gm = (size_t)blockIdx.x * 64 + mc8;
    const float* ap = A + gn * N2 + gm;

    // issue all 10 loads up front (MLP)
    float4 av[10];
    #pragma unroll
    for (int e = 0; e < 5; e++) {
        av[2 * e]     = *(const float4*)(ap + (size_t)e * NN);
        av[2 * e + 1] = *(const float4*)(ap + (size_t)e * NN + 4);
    }

    float acc[6][8] = {};
    #pragma unroll
    for (int e = 0; e < 5; e++) {
        const float a[8] = {av[2*e].x, av[2*e].y, av[2*e].z, av[2*e].w,
                            av[2*e+1].x, av[2*e+1].y, av[2*e+1].z, av[2*e+1].w};
        #pragma unroll
        for (int c = 0; c < 2; c++) {
            const float q0 = s[0][c][e], q1 = s[1][c][e], q2 = s[2][c][e];
            #pragma unroll
            for (int i = 0; i < 8; i++) {
                acc[c][i]     += q0 * a[i];
                acc[2 + c][i] += q1 * a[i];
                acc[4 + c][i] += q2 * a[i];
            }
        }
    }

    // HA row-major, 16B stores (128B segments per 8 lanes)
    #pragma unroll
    for (int c = 0; c < 2; c++) {
        u16x8 v;
        #pragma unroll
        for (int i = 0; i < 8; i++) v[i] = f2bf(acc[c][i]);
        *(u16x8*)&HA[(size_t)c * NN + gn * N2 + gm] = v;
    }

    // partial row sums of HB2-combine (for b2sum)
    #pragma unroll
    for (int c = 0; c < 2; c++) {
        float v = 0.f;
        #pragma unroll
        for (int i = 0; i < 8; i++) v += acc[4 + c][i];
        v += __shfl_xor(v, 1);
        v += __shfl_xor(v, 2);
        v += __shfl_xor(v, 4);
        if ((tid & 7) == 0)
            PB2[(size_t)c * 32 * 2048 + (size_t)blockIdx.x * 2048 + gn] = v;
    }

    // transposed outputs, 2 rounds of 2 channels through fp32 LDS tile
    #pragma unroll
    for (int rr = 0; rr < 2; rr++) {
        __syncthreads();
        #pragma unroll
        for (int rl = 0; rl < 2; rl++)
            #pragma unroll
            for (int i = 0; i < 8; i++)
                tile[rl][mc8 + i][nr] = acc[2 + rr * 2 + rl][i];
        __syncthreads();
        #pragma unroll
        for (int rl = 0; rl < 2; rl++) {
            const float4 t0 = *(const float4*)&tile[rl][nr][mc8];
            const float4 t1 = *(const float4*)&tile[rl][nr][mc8 + 4];
            u16x8 v;
            v[0] = f2bf(t0.x); v[1] = f2bf(t0.y); v[2] = f2bf(t0.z); v[3] = f2bf(t0.w);
            v[4] = f2bf(t1.x); v[5] = f2bf(t1.y); v[6] = f2bf(t1.z); v[7] = f2bf(t1.w);
            unsigned short* dst = (rr == 0 ? HBt : HB2t) + (size_t)rl * NN
                + ((size_t)blockIdx.x * 64 + nr) * N2
                + (size_t)blockIdx.y * 64 + mc8;
            *(u16x8*)dst = v;
        }
    }
}

// ---------------------------------------------------------------------------
// b2sum[c][n] = sum_bx PB2[c][bx][n]
// ---------------------------------------------------------------------------
__global__ __launch_bounds__(256) void b2fold_kernel(
    const float* __restrict__ PB2, float* __restrict__ b2sum) {
    const int r = blockIdx.x * 256 + threadIdx.x;   // c*2048 + n
    const int c = r >> 11, n = r & 2047;
    float sum = 0.f;
    #pragma unroll
    for (int bx = 0; bx < 32; bx++) sum += PB2[c * 65536 + bx * 2048 + n];
    b2sum[r] = sum;
}

// ---------------------------------------------------------------------------
// bf16 GEMM, B^T input: C[c] = A[c] @ B[c].
// 256x128 tile, BK=64, 8 waves (4Mx2N), per-wave 64x64 (4x4 frags 16x16x32).
// 3-deep counted-vmcnt pipeline, XOR-swizzled LDS, setprio around MFMA.
// MODE 0: bf16 C store + deterministic per-block partial row sums P.
// MODE 1: fp32 C store scaled by sfac[row] (final H).
// ---------------------------------------------------------------------------
#define GBM 256
#define GBN 128
#define GBK 64
#define TILE_SHORTS 24576   // 48KB in shorts
#define A_SHORTS    16384   // A region per buffer

template <int MODE>
__global__ __launch_bounds__(512, 2) void gemm_bt2(
    const unsigned short* __restrict__ A, const unsigned short* __restrict__ Bt,
    void* __restrict__ Cout, float* __restrict__ P,
    const float* __restrict__ sfac) {
    __shared__ unsigned short lds[3 * TILE_SHORTS];   // 144 KB

    const int tid  = threadIdx.x;
    const int wave = tid >> 6, lane = tid & 63;
    const int wr = (wave >> 1) * 64;    // 0,64,128,192
    const int wc = (wave & 1) * 64;     // 0,64
    const int l16 = lane & 15, lhi = lane >> 4;
    const int lsw = l16 & 7;            // row-dependent swizzle bits on read

    const int brow = blockIdx.y * GBM;
    const int bcol = blockIdx.x * GBN;
    const size_t cz = (size_t)blockIdx.z * NN;
    const unsigned short* Ab  = A  + cz + (size_t)brow * N2;
    const unsigned short* Btb = Bt + cz + (size_t)bcol * N2;

    const unsigned short* a_src[4];
    #pragma unroll
    for (int i = 0; i < 4; i++) {
        const int slot = i * 512 + tid;
        const int r = slot >> 3, ssw = (slot & 7) ^ (r & 7);
        a_src[i] = Ab + (size_t)r * N2 + ssw * 8;
    }
    const unsigned short* b_src[2];
    #pragma unroll
    for (int i = 0; i < 2; i++) {
        const int slot = i * 512 + tid;
        const int r = slot >> 3, ssw = (slot & 7) ^ (r & 7);
        b_src[i] = Btb + (size_t)r * N2 + ssw * 8;
    }

    #define STAGE(buf, k0)                                                    \
        do {                                                                  \
            unsigned short* dst = lds + (buf) * TILE_SHORTS + tid * 8;        \
            _Pragma("unroll")                                                 \
            for (int i = 0; i < 4; i++)                                       \
                gload16(a_src[i] + (k0), dst + i * 4096);                     \
            _Pragma("unroll")                                                 \
            for (int i = 0; i < 2; i++)                                       \
                gload16(b_src[i] + (k0), dst + A_SHORTS + i * 4096);          \
        } while (0)

    f32x4 acc[4][4] = {};

    STAGE(0, 0);
    STAGE(1, GBK);

    const int nt = N2 / GBK;   // 32
    for (int t = 0; t < nt; ++t) {
        if (t + 2 < nt) STAGE((t + 2) % 3, (t + 2) * GBK);

        if (t < nt - 2)       asm volatile("s_waitcnt vmcnt(12)" ::: "memory");
        else if (t == nt - 2) asm volatile("s_waitcnt vmcnt(6)"  ::: "memory");
        else                  asm volatile("s_waitcnt vmcnt(0)"  ::: "memory");
        __builtin_amdgcn_s_barrier();          // buf[t%3] ready for all waves

        const unsigned short* base = lds + (t % 3) * TILE_SHORTS;
        short8 af[4][2], bf[4][2];
        #pragma unroll
        for (int m = 0; m < 4; m++) {
            const unsigned short* rowp = base + (wr + m * 16 + l16) * 64;
            #pragma unroll
            for (int ks = 0; ks < 2; ks++)
                af[m][ks] = *(const short8*)(rowp + ((ks * 4 + lhi) ^ lsw) * 8);
        }
        #pragma unroll
        for (int n = 0; n < 4; n++) {
            const unsigned short* rowp = base + A_SHORTS + (wc + n * 16 + l16) * 64;
            #pragma unroll
            for (int ks = 0; ks < 2; ks++)
                bf[n][ks] = *(const short8*)(rowp + ((ks * 4 + lhi) ^ lsw) * 8);
        }

        __builtin_amdgcn_s_setprio(1);
        #pragma unroll
        for (int ks = 0; ks < 2; ks++)
            #pragma unroll
            for (int m = 0; m < 4; m++)
                #pragma unroll
                for (int n = 0; n < 4; n++)
                    acc[m][n] = __builtin_amdgcn_mfma_f32_16x16x32_bf16(
                        af[m][ks], bf[n][ks], acc[m][n], 0, 0, 0);
        __builtin_amdgcn_s_setprio(0);

        asm volatile("s_waitcnt lgkmcnt(0)" ::: "memory");
        __builtin_amdgcn_sched_barrier(0);
        __builtin_amdgcn_s_barrier();          // all waves done reading buf[t%3]
    }
    #undef STAGE

    if constexpr (MODE == 0) {
        // bf16 store + partial row sums
        unsigned short* Cb = (unsigned short*)Cout + cz + (size_t)brow * N2 + bcol;
        #pragma unroll
        for (int m = 0; m < 4; m++) {
            const int r0 = wr + m * 16 + lhi * 4;
            #pragma unroll
            for (int n = 0; n < 4; n++) {
                const int c0 = wc + n * 16 + l16;
                #pragma unroll
                for (int j = 0; j < 4; j++)
                    Cb[(size_t)(r0 + j) * N2 + c0] = f2bf(acc[m][n][j]);
            }
        }
        const size_t pb = (size_t)(blockIdx.x * 2 + (wave & 1)) * 4096
                        + (size_t)blockIdx.z * 2048 + brow + wr;
        #pragma unroll
        for (int m = 0; m < 4; m++)
            #pragma unroll
            for (int j = 0; j < 4; j++) {
                float ps = acc[m][0][j] + acc[m][1][j] + acc[m][2][j] + acc[m][3][j];
                ps += __shfl_xor(ps, 1);
                ps += __shfl_xor(ps, 2);
                ps += __shfl_xor(ps, 4);
                ps += __shfl_xor(ps, 8);
                if (l16 == 0) P[pb + m * 16 + lhi * 4 + j] = ps;
            }
    } else {
        // fp32 store scaled by sfac[row] -> final H
        float* Cb = (float*)Cout + cz + (size_t)brow * N2 + bcol;
        float sf[4][4];
        #pragma unroll
        for (int m = 0; m < 4; m++)
            #pragma unroll
            for (int j = 0; j < 4; j++)
                sf[m][j] = sfac[blockIdx.z * 2048 + brow + wr + m * 16 + lhi * 4 + j];
        #pragma unroll
        for (int m = 0; m < 4; m++) {
            const int r0 = wr + m * 16 + lhi * 4;
            #pragma unroll
            for (int n = 0; n < 4; n++) {
                const int c0 = wc + n * 16 + l16;
                #pragma unroll
                for (int j = 0; j < 4; j++)
                    Cb[(size_t)(r0 + j) * N2 + c0] = acc[m][n][j] * sf[m][j];
            }
        }
    }
}

// ---------------------------------------------------------------------------
// dinv0[r] = rsqrt(sum_cb P[cb][r])  (0 if <=0)
// ---------------------------------------------------------------------------
__global__ __launch_bounds__(256) void dinv_kernel(
    const float* __restrict__ P, float* __restrict__ dinv) {
    const int r = blockIdx.x * 256 + threadIdx.x;
    float sum = 0.f;
    #pragma unroll
    for (int cb = 0; cb < 32; cb++) sum += P[cb * 4096 + r];
    dinv[r] = sum > 0.f ? rsqrtf(sum) : 0.f;
}

// ---------------------------------------------------------------------------
// sfac[r] = dinv0[r] * rsqrt(dinv0[r] * (C0[r,:] . b2sum))   (guarded)
// ---------------------------------------------------------------------------
__device__ __forceinline__ float block_sum256(float v) {
    #pragma unroll
    for (int off = 32; off; off >>= 1) v += __shfl_xor(v, off, 64);
    __shared__ float wsum[4];
    if ((threadIdx.x & 63) == 0) wsum[threadIdx.x >> 6] = v;
    __syncthreads();
    return wsum[0] + wsum[1] + wsum[2] + wsum[3];
}

__global__ __launch_bounds__(256) void gemv_sfac_kernel(
    const unsigned short* __restrict__ C0, const float* __restrict__ b2sum,
    const float* __restrict__ dinv0, float* __restrict__ sfac) {
    const size_t r = blockIdx.x;               // 0..4095 (c*2048 + row)
    const unsigned short* row = C0 + r * N2;
    const float* bs = b2sum + ((r >> 11) << 11);
    const int base = threadIdx.x * 8;
    const u16x8 v = *(const u16x8*)&row[base];
    float sum = 0.f;
    #pragma unroll
    for (int i = 0; i < 8; i++) sum += bf2f(v[i]) * bs[base + i];
    const float tot = block_sum256(sum);
    if (threadIdx.x == 0) {
        const float d0 = dinv0[r];
        const float d1 = d0 * tot;
        sfac[r] = d0 * (d1 > 0.f ? rsqrtf(d1) : 0.f);
    }
}

// ---------------------------------------------------------------------------
// head: 64 blocks x 8 targets. gcn_w read 64x instead of 512x.
// ---------------------------------------------------------------------------
__global__ __launch_bounds__(256) void head_kernel(
    const float* __restrict__ X, const float* __restrict__ gcn_w,
    const float* __restrict__ gcn_b, const float* __restrict__ lin_w,
    const float* __restrict__ lin_b, const int* __restrict__ tx,
    float* __restrict__ y) {
    __shared__ float xr[8][512];    // 16 KB
    __shared__ float xk[8][132];    // padded
    __shared__ int trg[8];
    const int tid = threadIdx.x, b = blockIdx.x;
    if (tid < 8) trg[tid] = tx[b * 8 + tid];
    __syncthreads();
    #pragma unroll
    for (int q = 0; q < 4; q++) {
        const int idx = q * 1024 + tid * 4;
        const int t = idx >> 9, col = idx & 511;
        *(float4*)&xr[t][col] = *(const float4*)&X[(size_t)trg[t] * 512 + col];
    }
    __syncthreads();
    const int k = tid & 127, tp = tid >> 7;    // tp: 0..1 -> targets tp*4..tp*4+3
    const float* wrp = gcn_w + (size_t)k * 512;
    float d[4] = {0.f, 0.f, 0.f, 0.f};
    for (int i = 0; i < 512; i += 4) {
        const float4 wv = *(const float4*)&wrp[i];
        #pragma unroll
        for (int tt = 0; tt < 4; tt++) {
            const float* xp = xr[tp * 4 + tt];
            d[tt] += xp[i] * wv.x + xp[i+1] * wv.y + xp[i+2] * wv.z + xp[i+3] * wv.w;
        }
    }
    const float gb = gcn_b[k];
    #pragma unroll
    for (int tt = 0; tt < 4; tt++) xk[tp * 4 + tt][k] = fmaxf(d[tt] + gb, 0.f);
    __syncthreads();
    if (tid < 64) {
        const int t = tid >> 3, o = tid & 7;
        float a = lin_b[o];
        const float* lw = lin_w + o * 256;
        for (int kk = 0; kk < 128; kk++)
            a += xk[t][kk] * (lw[kk] + lw[128 + kk]);
        y[(size_t)(b * 8 + t) * 8 + o] = a;
    }
}

__global__ void wsoft_kernel(const float* __restrict__ w01,
                             const float* __restrict__ w02,
                             const float* __restrict__ w11,
                             float* __restrict__ out) {
    const int tid = threadIdx.x;
    if (tid < 6) {
        const int wi = tid >> 1, c = tid & 1;
        const float* w = (wi == 0 ? w01 : (wi == 1 ? w02 : w11)) + c * 5;
        float mx = w[0];
        for (int e = 1; e < 5; e++) mx = fmaxf(mx, w[e]);
        float ex[5], sum = 0.f;
        for (int e = 0; e < 5; e++) { ex[e] = expf(w[e] - mx); sum += ex[e]; }
        for (int e = 0; e < 5; e++) out[tid * 5 + e] = ex[e] / sum;
    }
}

// ---------------------------------------------------------------------------
extern "C" void kernel_launch(void* const* d_in, const int* in_sizes, int n_in,
                              void* d_out, int out_size, void* d_ws, size_t ws_size,
                              hipStream_t stream) {
    const float* A     = (const float*)d_in[0];
    const float* X     = (const float*)d_in[1];
    const float* w01   = (const float*)d_in[2];
    const float* w02   = (const float*)d_in[3];
    const float* w11   = (const float*)d_in[4];
    const float* gcn_w = (const float*)d_in[5];
    const float* gcn_b = (const float*)d_in[6];
    const float* lin_w = (const float*)d_in[7];
    const float* lin_b = (const float*)d_in[8];
    const int*   tx    = (const int*)d_in[9];

    float* out  = (float*)d_out;
    float* y    = out;                 // [512, 8]
    float* allw = out + 4096;          // [3, 2, 5]
    float* H    = out + 4126;          // [2, 2048, 2048] fp32 final output

    unsigned short* HA   = (unsigned short*)d_ws;       // [2,N,N] bf16
    unsigned short* HBt  = HA + 2 * NN;                 // [2,N,N] bf16 (B^T)
    unsigned short* HB2t = HBt + 2 * NN;                // [2,N,N] bf16 (B^T)
    unsigned short* C0   = HB2t + 2 * NN;               // [2,N,N] bf16 layer-0 product
    float* P     = (float*)(C0 + 2 * NN);               // [32][4096] partials
    float* PB2   = P + 32 * 4096;                       // [2][32][2048]
    float* dinv0 = PB2 + 2 * 32 * 2048;                 // [4096]
    float* b2sum = dinv0 + 4096;                        // [4096]
    float* sfac  = b2sum + 4096;                        // [4096]

    combine_kernel<<<dim3(32, 32), 512, 0, stream>>>(A, w01, w02, w11,
                                                     HA, HBt, HB2t, PB2);
    b2fold_kernel<<<16, 256, 0, stream>>>(PB2, b2sum);
    gemm_bt2<0><<<dim3(16, 8, 2), 512, 0, stream>>>(HA, HBt, C0, P, nullptr);
    dinv_kernel<<<16, 256, 0, stream>>>(P, dinv0);
    gemv_sfac_kernel<<<4096, 256, 0, stream>>>(C0, b2sum, dinv0, sfac);
    gemm_bt2<1><<<dim3(16, 8, 2), 512, 0, stream>>>(C0, HB2t, H, nullptr, sfac);
    head_kernel<<<64, 256, 0, stream>>>(X, gcn_w, gcn_b, lin_w, lin_b, tx, y);
    wsoft_kernel<<<1, 64, 0, stream>>>(w01, w02, w11, allw);
}

// Round 6
// 143.452 us; speedup vs baseline: 1.0446x; 1.0446x over previous
//
#include <hip/hip_runtime.h>
#include <stdint.h>

#define N2 2048
#define NN (2048UL * 2048UL)

typedef __attribute__((ext_vector_type(8))) short short8;
typedef __attribute__((ext_vector_type(8))) unsigned short u16x8;
typedef __attribute__((ext_vector_type(4))) float f32x4;

__device__ __forceinline__ unsigned short f2bf(float f) {
    unsigned int u = __float_as_uint(f);
    u += 0x7FFFu + ((u >> 16) & 1u);   // round-to-nearest-even
    return (unsigned short)(u >> 16);
}
__device__ __forceinline__ float bf2f(unsigned short u) {
    return __uint_as_float((unsigned int)u << 16);
}

__device__ __forceinline__ void gload16(const void* g, void* l) {
    __builtin_amdgcn_global_load_lds(
        (const __attribute__((address_space(1))) unsigned int*)g,
        (__attribute__((address_space(3))) unsigned int*)l, 16, 0, 0);
}

// ---------------------------------------------------------------------------
// combine: HA[c][n][m]  = sum_e s1[c][e] A[e][n][m]   (bf16, row-major)
//          HBt[c][m][n] = sum_e s2[c][e] A[e][n][m]   (bf16, transposed)
//          HB2t[c][m][n]= sum_e s3[c][e] A[e][n][m]   (bf16, transposed)
//          PB2[c][bx][n] = partial row sums of HB2-combine over this m-block
// ---------------------------------------------------------------------------
__global__ __launch_bounds__(512, 4) void combine_kernel(
    const float* __restrict__ A, const float* __restrict__ w01,
    const float* __restrict__ w02, const float* __restrict__ w11,
    unsigned short* __restrict__ HA, unsigned short* __restrict__ HBt,
    unsigned short* __restrict__ HB2t, float* __restrict__ PB2) {
    __shared__ float s[3][2][5];
    __shared__ float tile[2][64][68];   // 34.8 KB
    const int tid = threadIdx.x;
    if (tid < 6) {
        const int wi = tid >> 1, c = tid & 1;
        const float* w = (wi == 0 ? w01 : (wi == 1 ? w02 : w11)) + c * 5;
        float mx = w[0];
        for (int e = 1; e < 5; e++) mx = fmaxf(mx, w[e]);
        float ex[5], sum = 0.f;
        for (int e = 0; e < 5; e++) { ex[e] = expf(w[e] - mx); sum += ex[e]; }
        for (int e = 0; e < 5; e++) s[wi][c][e] = ex[e] / sum;
    }
    __syncthreads();

    const int nr  = tid >> 3;          // 0..63
    const int mc8 = (tid & 7) * 8;     // 0..56
    const size_t gn = (size_t)blockIdx.y * 64 + nr;
    const size_t gm = (size_t)blockIdx.x * 64 + mc8;
    const float* ap = A + gn * N2 + gm;

    float4 av[10];
    #pragma unroll
    for (int e = 0; e < 5; e++) {
        av[2 * e]     = *(const float4*)(ap + (size_t)e * NN);
        av[2 * e + 1] = *(const float4*)(ap + (size_t)e * NN + 4);
    }

    float acc[6][8] = {};
    #pragma unroll
    for (int e = 0; e < 5; e++) {
        const float a[8] = {av[2*e].x, av[2*e].y, av[2*e].z, av[2*e].w,
                            av[2*e+1].x, av[2*e+1].y, av[2*e+1].z, av[2*e+1].w};
        #pragma unroll
        for (int c = 0; c < 2; c++) {
            const float q0 = s[0][c][e], q1 = s[1][c][e], q2 = s[2][c][e];
            #pragma unroll
            for (int i = 0; i < 8; i++) {
                acc[c][i]     += q0 * a[i];
                acc[2 + c][i] += q1 * a[i];
                acc[4 + c][i] += q2 * a[i];
            }
        }
    }

    #pragma unroll
    for (int c = 0; c < 2; c++) {
        u16x8 v;
        #pragma unroll
        for (int i = 0; i < 8; i++) v[i] = f2bf(acc[c][i]);
        *(u16x8*)&HA[(size_t)c * NN + gn * N2 + gm] = v;
    }

    #pragma unroll
    for (int c = 0; c < 2; c++) {
        float v = 0.f;
        #pragma unroll
        for (int i = 0; i < 8; i++) v += acc[4 + c][i];
        v += __shfl_xor(v, 1);
        v += __shfl_xor(v, 2);
        v += __shfl_xor(v, 4);
        if ((tid & 7) == 0)
            PB2[(size_t)c * 32 * 2048 + (size_t)blockIdx.x * 2048 + gn] = v;
    }

    #pragma unroll
    for (int rr = 0; rr < 2; rr++) {
        __syncthreads();
        #pragma unroll
        for (int rl = 0; rl < 2; rl++)
            #pragma unroll
            for (int i = 0; i < 8; i++)
                tile[rl][mc8 + i][nr] = acc[2 + rr * 2 + rl][i];
        __syncthreads();
        #pragma unroll
        for (int rl = 0; rl < 2; rl++) {
            const float4 t0 = *(const float4*)&tile[rl][nr][mc8];
            const float4 t1 = *(const float4*)&tile[rl][nr][mc8 + 4];
            u16x8 v;
            v[0] = f2bf(t0.x); v[1] = f2bf(t0.y); v[2] = f2bf(t0.z); v[3] = f2bf(t0.w);
            v[4] = f2bf(t1.x); v[5] = f2bf(t1.y); v[6] = f2bf(t1.z); v[7] = f2bf(t1.w);
            unsigned short* dst = (rr == 0 ? HBt : HB2t) + (size_t)rl * NN
                + ((size_t)blockIdx.x * 64 + nr) * N2
                + (size_t)blockIdx.y * 64 + mc8;
            *(u16x8*)dst = v;
        }
    }
}

// ---------------------------------------------------------------------------
// b2sum[c][n] = sum_bx PB2[c][bx][n]
// ---------------------------------------------------------------------------
__global__ __launch_bounds__(256) void b2fold_kernel(
    const float* __restrict__ PB2, float* __restrict__ b2sum) {
    const int r = blockIdx.x * 256 + threadIdx.x;   // c*2048 + n
    const int c = r >> 11, n = r & 2047;
    float sum = 0.f;
    #pragma unroll
    for (int bx = 0; bx < 32; bx++) sum += PB2[c * 65536 + bx * 2048 + n];
    b2sum[r] = sum;
}

// ---------------------------------------------------------------------------
// bf16 GEMM, B^T input: C[c] = A[c] @ B[c].
// 256x128 tile, BK=64, 8 waves (4Mx2N), per-wave 64x64 (4x4 frags 16x16x32).
// 2 phases per K-tile; RACE-FIXED ordering per phase:
//   {vmcnt(counted) -> s_barrier -> ds_reads -> stage-issue ->
//    lgkmcnt(0)+sched_barrier -> setprio(1) MFMA setprio(0)}
// The barrier sits BETWEEN the per-wave vmcnt confirmation and the ds_reads,
// so the tile is consistent across all 8 staging waves (round-5 bug: ds_read
// before barrier read other waves' unfinished global_load_lds).
// 2 LDS buffers (96KB); stage FIFO in consumption order
// [A-half0 (2) | B (2) | A-half1 (2)]; vmcnt never 0 in the loop.
// MODE 0: bf16 C store + per-block partial row sums P.
// MODE 1: fp32 C store scaled by sfac[row] (final H).
// ---------------------------------------------------------------------------
#define GBM 256
#define GBN 128
#define GBK 64
#define BUF_SHORTS 24576   // 48KB per buffer

template <int MODE>
__global__ __launch_bounds__(512, 2) void gemm_bt3(
    const unsigned short* __restrict__ A, const unsigned short* __restrict__ Bt,
    void* __restrict__ Cout, float* __restrict__ P,
    const float* __restrict__ sfac) {
    __shared__ unsigned short lds[2 * BUF_SHORTS];   // 96 KB

    const int tid  = threadIdx.x;
    const int wave = tid >> 6, lane = tid & 63;
    const int wm = wave >> 1, wn = wave & 1;
    const int wr = wm * 64;             // 0,64,128,192
    const int wc = wn * 64;             // 0,64
    const int l16 = lane & 15, lhi = lane >> 4;
    const int lsw = l16 & 7;            // row-dependent swizzle bits

    const int brow = blockIdx.y * GBM;
    const int bcol = blockIdx.x * GBN;
    const size_t cz = (size_t)blockIdx.z * NN;
    const unsigned short* Ab  = A  + cz + (size_t)brow * N2;
    const unsigned short* Btb = Bt + cz + (size_t)bcol * N2;

    // 6 stage loads per thread, FIFO order = consumption order.
    // L0,L1: A rows (r&63)<32 ; L2,L3: B ; L4,L5: A rows (r&63)>=32.
    const unsigned short* src[6];
    #pragma unroll
    for (int L = 0; L < 6; L++) {
        const int g = L * 512 + tid;
        int r, s;
        const unsigned short* basep;
        if (g < 1024) {                       // A half0
            r = (g >> 8) * 64 + ((g >> 3) & 31);
            s = (g & 7) ^ (r & 7);
            basep = Ab;
        } else if (g < 2048) {                // B
            const int h = g - 1024;
            r = h >> 3;
            s = (h & 7) ^ (r & 7);
            basep = Btb;
        } else {                              // A half1
            const int h = g - 2048;
            r = (h >> 8) * 64 + 32 + ((h >> 3) & 31);
            s = (h & 7) ^ (r & 7);
            basep = Ab;
        }
        src[L] = basep + (size_t)r * N2 + s * 8;
    }

    #define STAGE3(buf, k0, L0_)                                              \
        do {                                                                  \
            unsigned short* dst = lds + (buf) * BUF_SHORTS                    \
                                + ((L0_) * 512 + tid) * 8;                    \
            _Pragma("unroll")                                                 \
            for (int i = 0; i < 3; i++)                                       \
                gload16(src[(L0_) + i] + (k0), dst + i * 4096);               \
        } while (0)

    f32x4 acc[4][4] = {};

    // prologue: all 6 chunks of tile 0 into buf 0
    STAGE3(0, 0, 0);
    STAGE3(0, 0, 3);

    const int nt = N2 / GBK;   // 32
    for (int t = 0; t < nt; ++t) {
        const int p = t & 1;
        const unsigned short* base = lds + p * BUF_SHORTS;
        unsigned short* nbase = lds + (p ^ 1) * BUF_SHORTS;
        const int nk0 = ((t + 1) == nt ? 0 : (t + 1)) * GBK;  // wrap: in-bounds, unused

        // ---------------- phase A: m-frags 0,1 ----------------
        // own L0..L3(t) confirmed, then JOIN ALL WAVES, then read.
        asm volatile("s_waitcnt vmcnt(2)" ::: "memory");
        __builtin_amdgcn_s_barrier();
        __builtin_amdgcn_sched_barrier(0);
        short8 af0[2][2], bfr[4][2];
        #pragma unroll
        for (int m = 0; m < 2; m++) {
            const unsigned short* rowp = base + wm * 2048 + (m * 16 + l16) * 64;
            #pragma unroll
            for (int ks = 0; ks < 2; ks++)
                af0[m][ks] = *(const short8*)(rowp + (((ks * 4 + lhi) ^ lsw) * 8));
        }
        #pragma unroll
        for (int n = 0; n < 4; n++) {
            const unsigned short* rowp = base + 8192 + (wc + n * 16 + l16) * 64;
            #pragma unroll
            for (int ks = 0; ks < 2; ks++)
                bfr[n][ks] = *(const short8*)(rowp + (((ks * 4 + lhi) ^ lsw) * 8));
        }
        {
            unsigned short* dst = nbase + tid * 8;
            #pragma unroll
            for (int i = 0; i < 3; i++)
                gload16(src[i] + nk0, dst + i * 4096);
        }
        asm volatile("s_waitcnt lgkmcnt(0)" ::: "memory");
        __builtin_amdgcn_sched_barrier(0);
        __builtin_amdgcn_s_setprio(1);
        #pragma unroll
        for (int ks = 0; ks < 2; ks++)
            #pragma unroll
            for (int m = 0; m < 2; m++)
                #pragma unroll
                for (int n = 0; n < 4; n++)
                    acc[m][n] = __builtin_amdgcn_mfma_f32_16x16x32_bf16(
                        af0[m][ks], bfr[n][ks], acc[m][n], 0, 0, 0);
        __builtin_amdgcn_s_setprio(0);

        // ---------------- phase B: m-frags 2,3 ----------------
        asm volatile("s_waitcnt vmcnt(3)" ::: "memory");
        __builtin_amdgcn_s_barrier();
        __builtin_amdgcn_sched_barrier(0);
        short8 af1[2][2];
        #pragma unroll
        for (int m = 0; m < 2; m++) {
            const unsigned short* rowp = base + 16384 + wm * 2048 + (m * 16 + l16) * 64;
            #pragma unroll
            for (int ks = 0; ks < 2; ks++)
                af1[m][ks] = *(const short8*)(rowp + (((ks * 4 + lhi) ^ lsw) * 8));
        }
        {
            unsigned short* dst = nbase + (3 * 512 + tid) * 8;
            #pragma unroll
            for (int i = 0; i < 3; i++)
                gload16(src[3 + i] + nk0, dst + i * 4096);
        }
        asm volatile("s_waitcnt lgkmcnt(0)" ::: "memory");
        __builtin_amdgcn_sched_barrier(0);
        __builtin_amdgcn_s_setprio(1);
        #pragma unroll
        for (int ks = 0; ks < 2; ks++)
            #pragma unroll
            for (int m = 0; m < 2; m++)
                #pragma unroll
                for (int n = 0; n < 4; n++)
                    acc[2 + m][n] = __builtin_amdgcn_mfma_f32_16x16x32_bf16(
                        af1[m][ks], bfr[n][ks], acc[2 + m][n], 0, 0, 0);
        __builtin_amdgcn_s_setprio(0);
    }
    #undef STAGE3

    if constexpr (MODE == 0) {
        unsigned short* Cb = (unsigned short*)Cout + cz + (size_t)brow * N2 + bcol;
        #pragma unroll
        for (int m = 0; m < 4; m++) {
            const int r0 = wr + m * 16 + lhi * 4;
            #pragma unroll
            for (int n = 0; n < 4; n++) {
                const int c0 = wc + n * 16 + l16;
                #pragma unroll
                for (int j = 0; j < 4; j++)
                    Cb[(size_t)(r0 + j) * N2 + c0] = f2bf(acc[m][n][j]);
            }
        }
        const size_t pb = (size_t)(blockIdx.x * 2 + wn) * 4096
                        + (size_t)blockIdx.z * 2048 + brow + wr;
        #pragma unroll
        for (int m = 0; m < 4; m++)
            #pragma unroll
            for (int j = 0; j < 4; j++) {
                float ps = acc[m][0][j] + acc[m][1][j] + acc[m][2][j] + acc[m][3][j];
                ps += __shfl_xor(ps, 1);
                ps += __shfl_xor(ps, 2);
                ps += __shfl_xor(ps, 4);
                ps += __shfl_xor(ps, 8);
                if (l16 == 0) P[pb + m * 16 + lhi * 4 + j] = ps;
            }
    } else {
        float* Cb = (float*)Cout + cz + (size_t)brow * N2 + bcol;
        float sf[4][4];
        #pragma unroll
        for (int m = 0; m < 4; m++)
            #pragma unroll
            for (int j = 0; j < 4; j++)
                sf[m][j] = sfac[blockIdx.z * 2048 + brow + wr + m * 16 + lhi * 4 + j];
        #pragma unroll
        for (int m = 0; m < 4; m++) {
            const int r0 = wr + m * 16 + lhi * 4;
            #pragma unroll
            for (int n = 0; n < 4; n++) {
                const int c0 = wc + n * 16 + l16;
                #pragma unroll
                for (int j = 0; j < 4; j++)
                    Cb[(size_t)(r0 + j) * N2 + c0] = acc[m][n][j] * sf[m][j];
            }
        }
    }
}

// ---------------------------------------------------------------------------
// dinv0[r] = rsqrt(sum_cb P[cb][r])  (0 if <=0)
// ---------------------------------------------------------------------------
__global__ __launch_bounds__(256) void dinv_kernel(
    const float* __restrict__ P, float* __restrict__ dinv) {
    const int r = blockIdx.x * 256 + threadIdx.x;
    float sum = 0.f;
    #pragma unroll
    for (int cb = 0; cb < 32; cb++) sum += P[cb * 4096 + r];
    dinv[r] = sum > 0.f ? rsqrtf(sum) : 0.f;
}

// ---------------------------------------------------------------------------
// sfac[r] = dinv0[r] * rsqrt(dinv0[r] * (C0[r,:] . b2sum))   (guarded)
// ---------------------------------------------------------------------------
__device__ __forceinline__ float block_sum256(float v) {
    #pragma unroll
    for (int off = 32; off; off >>= 1) v += __shfl_xor(v, off, 64);
    __shared__ float wsum[4];
    if ((threadIdx.x & 63) == 0) wsum[threadIdx.x >> 6] = v;
    __syncthreads();
    return wsum[0] + wsum[1] + wsum[2] + wsum[3];
}

__global__ __launch_bounds__(256) void gemv_sfac_kernel(
    const unsigned short* __restrict__ C0, const float* __restrict__ b2sum,
    const float* __restrict__ dinv0, float* __restrict__ sfac) {
    const size_t r = blockIdx.x;               // 0..4095 (c*2048 + row)
    const unsigned short* row = C0 + r * N2;
    const float* bs = b2sum + ((r >> 11) << 11);
    const int base = threadIdx.x * 8;
    const u16x8 v = *(const u16x8*)&row[base];
    float sum = 0.f;
    #pragma unroll
    for (int i = 0; i < 8; i++) sum += bf2f(v[i]) * bs[base + i];
    const float tot = block_sum256(sum);
    if (threadIdx.x == 0) {
        const float d0 = dinv0[r];
        const float d1 = d0 * tot;
        sfac[r] = d0 * (d1 > 0.f ? rsqrtf(d1) : 0.f);
    }
}

// ---------------------------------------------------------------------------
// head: 64 blocks x 8 targets.
// ---------------------------------------------------------------------------
__global__ __launch_bounds__(256) void head_kernel(
    const float* __restrict__ X, const float* __restrict__ gcn_w,
    const float* __restrict__ gcn_b, const float* __restrict__ lin_w,
    const float* __restrict__ lin_b, const int* __restrict__ tx,
    float* __restrict__ y) {
    __shared__ float xr[8][512];    // 16 KB
    __shared__ float xk[8][132];    // padded
    __shared__ int trg[8];
    const int tid = threadIdx.x, b = blockIdx.x;
    if (tid < 8) trg[tid] = tx[b * 8 + tid];
    __syncthreads();
    #pragma unroll
    for (int q = 0; q < 4; q++) {
        const int idx = q * 1024 + tid * 4;
        const int t = idx >> 9, col = idx & 511;
        *(float4*)&xr[t][col] = *(const float4*)&X[(size_t)trg[t] * 512 + col];
    }
    __syncthreads();
    const int k = tid & 127, tp = tid >> 7;
    const float* wrp = gcn_w + (size_t)k * 512;
    float d[4] = {0.f, 0.f, 0.f, 0.f};
    for (int i = 0; i < 512; i += 4) {
        const float4 wv = *(const float4*)&wrp[i];
        #pragma unroll
        for (int tt = 0; tt < 4; tt++) {
            const float* xp = xr[tp * 4 + tt];
            d[tt] += xp[i] * wv.x + xp[i+1] * wv.y + xp[i+2] * wv.z + xp[i+3] * wv.w;
        }
    }
    const float gb = gcn_b[k];
    #pragma unroll
    for (int tt = 0; tt < 4; tt++) xk[tp * 4 + tt][k] = fmaxf(d[tt] + gb, 0.f);
    __syncthreads();
    if (tid < 64) {
        const int t = tid >> 3, o = tid & 7;
        float a = lin_b[o];
        const float* lw = lin_w + o * 256;
        for (int kk = 0; kk < 128; kk++)
            a += xk[t][kk] * (lw[kk] + lw[128 + kk]);
        y[(size_t)(b * 8 + t) * 8 + o] = a;
    }
}

__global__ void wsoft_kernel(const float* __restrict__ w01,
                             const float* __restrict__ w02,
                             const float* __restrict__ w11,
                             float* __restrict__ out) {
    const int tid = threadIdx.x;
    if (tid < 6) {
        const int wi = tid >> 1, c = tid & 1;
        const float* w = (wi == 0 ? w01 : (wi == 1 ? w02 : w11)) + c * 5;
        float mx = w[0];
        for (int e = 1; e < 5; e++) mx = fmaxf(mx, w[e]);
        float ex[5], sum = 0.f;
        for (int e = 0; e < 5; e++) { ex[e] = expf(w[e] - mx); sum += ex[e]; }
        for (int e = 0; e < 5; e++) out[tid * 5 + e] = ex[e] / sum;
    }
}

// ---------------------------------------------------------------------------
extern "C" void kernel_launch(void* const* d_in, const int* in_sizes, int n_in,
                              void* d_out, int out_size, void* d_ws, size_t ws_size,
                              hipStream_t stream) {
    const float* A     = (const float*)d_in[0];
    const float* X     = (const float*)d_in[1];
    const float* w01   = (const float*)d_in[2];
    const float* w02   = (const float*)d_in[3];
    const float* w11   = (const float*)d_in[4];
    const float* gcn_w = (const float*)d_in[5];
    const float* gcn_b = (const float*)d_in[6];
    const float* lin_w = (const float*)d_in[7];
    const float* lin_b = (const float*)d_in[8];
    const int*   tx    = (const int*)d_in[9];

    float* out  = (float*)d_out;
    float* y    = out;                 // [512, 8]
    float* allw = out + 4096;          // [3, 2, 5]
    float* H    = out + 4126;          // [2, 2048, 2048] fp32 final output

    unsigned short* HA   = (unsigned short*)d_ws;       // [2,N,N] bf16
    unsigned short* HBt  = HA + 2 * NN;                 // [2,N,N] bf16 (B^T)
    unsigned short* HB2t = HBt + 2 * NN;                // [2,N,N] bf16 (B^T)
    unsigned short* C0   = HB2t + 2 * NN;               // [2,N,N] bf16 layer-0 product
    float* P     = (float*)(C0 + 2 * NN);               // [32][4096] partials
    float* PB2   = P + 32 * 4096;                       // [2][32][2048]
    float* dinv0 = PB2 + 2 * 32 * 2048;                 // [4096]
    float* b2sum = dinv0 + 4096;                        // [4096]
    float* sfac  = b2sum + 4096;                        // [4096]

    combine_kernel<<<dim3(32, 32), 512, 0, stream>>>(A, w01, w02, w11,
                                                     HA, HBt, HB2t, PB2);
    b2fold_kernel<<<16, 256, 0, stream>>>(PB2, b2sum);
    gemm_bt3<0><<<dim3(16, 8, 2), 512, 0, stream>>>(HA, HBt, C0, P, nullptr);
    dinv_kernel<<<16, 256, 0, stream>>>(P, dinv0);
    gemv_sfac_kernel<<<4096, 256, 0, stream>>>(C0, b2sum, dinv0, sfac);
    gemm_bt3<1><<<dim3(16, 8, 2), 512, 0, stream>>>(C0, HB2t, H, nullptr, sfac);
    head_kernel<<<64, 256, 0, stream>>>(X, gcn_w, gcn_b, lin_w, lin_b, tx, y);
    wsoft_kernel<<<1, 64, 0, stream>>>(w01, w02, w11, allw);
}

// Round 7
// 134.769 us; speedup vs baseline: 1.1119x; 1.0644x over previous
//
#include <hip/hip_runtime.h>
#include <stdint.h>

#define N2 2048
#define NN (2048UL * 2048UL)

typedef __attribute__((ext_vector_type(8))) short short8;
typedef __attribute__((ext_vector_type(8))) unsigned short u16x8;
typedef __attribute__((ext_vector_type(4))) float f32x4;

__device__ __forceinline__ unsigned short f2bf(float f) {
    unsigned int u = __float_as_uint(f);
    u += 0x7FFFu + ((u >> 16) & 1u);   // round-to-nearest-even
    return (unsigned short)(u >> 16);
}
__device__ __forceinline__ float bf2f(unsigned short u) {
    return __uint_as_float((unsigned int)u << 16);
}

__device__ __forceinline__ void gload16(const void* g, void* l) {
    __builtin_amdgcn_global_load_lds(
        (const __attribute__((address_space(1))) unsigned int*)g,
        (__attribute__((address_space(3))) unsigned int*)l, 16, 0, 0);
}

// ---------------------------------------------------------------------------
// combine: HA[c][n][m]  = sum_e s1[c][e] A[e][n][m]   (bf16, row-major)
//          HBt[c][m][n] = sum_e s2[c][e] A[e][n][m]   (bf16, transposed)
//          HB2t[c][m][n]= sum_e s3[c][e] A[e][n][m]   (bf16, transposed)
//          PB2[c][bx][n] = partial row sums of HB2-combine over this m-block
// ---------------------------------------------------------------------------
__global__ __launch_bounds__(512, 4) void combine_kernel(
    const float* __restrict__ A, const float* __restrict__ w01,
    const float* __restrict__ w02, const float* __restrict__ w11,
    unsigned short* __restrict__ HA, unsigned short* __restrict__ HBt,
    unsigned short* __restrict__ HB2t, float* __restrict__ PB2) {
    __shared__ float s[3][2][5];
    __shared__ float tile[2][64][68];   // 34.8 KB
    const int tid = threadIdx.x;
    if (tid < 6) {
        const int wi = tid >> 1, c = tid & 1;
        const float* w = (wi == 0 ? w01 : (wi == 1 ? w02 : w11)) + c * 5;
        float mx = w[0];
        for (int e = 1; e < 5; e++) mx = fmaxf(mx, w[e]);
        float ex[5], sum = 0.f;
        for (int e = 0; e < 5; e++) { ex[e] = expf(w[e] - mx); sum += ex[e]; }
        for (int e = 0; e < 5; e++) s[wi][c][e] = ex[e] / sum;
    }
    __syncthreads();

    const int nr  = tid >> 3;          // 0..63
    const int mc8 = (tid & 7) * 8;     // 0..56
    const size_t gn = (size_t)blockIdx.y * 64 + nr;
    const size_t gm = (size_t)blockIdx.x * 64 + mc8;
    const float* ap = A + gn * N2 + gm;

    float4 av[10];
    #pragma unroll
    for (int e = 0; e < 5; e++) {
        av[2 * e]     = *(const float4*)(ap + (size_t)e * NN);
        av[2 * e + 1] = *(const float4*)(ap + (size_t)e * NN + 4);
    }

    float acc[6][8] = {};
    #pragma unroll
    for (int e = 0; e < 5; e++) {
        const float a[8] = {av[2*e].x, av[2*e].y, av[2*e].z, av[2*e].w,
                            av[2*e+1].x, av[2*e+1].y, av[2*e+1].z, av[2*e+1].w};
        #pragma unroll
        for (int c = 0; c < 2; c++) {
            const float q0 = s[0][c][e], q1 = s[1][c][e], q2 = s[2][c][e];
            #pragma unroll
            for (int i = 0; i < 8; i++) {
                acc[c][i]     += q0 * a[i];
                acc[2 + c][i] += q1 * a[i];
                acc[4 + c][i] += q2 * a[i];
            }
        }
    }

    #pragma unroll
    for (int c = 0; c < 2; c++) {
        u16x8 v;
        #pragma unroll
        for (int i = 0; i < 8; i++) v[i] = f2bf(acc[c][i]);
        *(u16x8*)&HA[(size_t)c * NN + gn * N2 + gm] = v;
    }

    #pragma unroll
    for (int c = 0; c < 2; c++) {
        float v = 0.f;
        #pragma unroll
        for (int i = 0; i < 8; i++) v += acc[4 + c][i];
        v += __shfl_xor(v, 1);
        v += __shfl_xor(v, 2);
        v += __shfl_xor(v, 4);
        if ((tid & 7) == 0)
            PB2[(size_t)c * 32 * 2048 + (size_t)blockIdx.x * 2048 + gn] = v;
    }

    #pragma unroll
    for (int rr = 0; rr < 2; rr++) {
        __syncthreads();
        #pragma unroll
        for (int rl = 0; rl < 2; rl++)
            #pragma unroll
            for (int i = 0; i < 8; i++)
                tile[rl][mc8 + i][nr] = acc[2 + rr * 2 + rl][i];
        __syncthreads();
        #pragma unroll
        for (int rl = 0; rl < 2; rl++) {
            const float4 t0 = *(const float4*)&tile[rl][nr][mc8];
            const float4 t1 = *(const float4*)&tile[rl][nr][mc8 + 4];
            u16x8 v;
            v[0] = f2bf(t0.x); v[1] = f2bf(t0.y); v[2] = f2bf(t0.z); v[3] = f2bf(t0.w);
            v[4] = f2bf(t1.x); v[5] = f2bf(t1.y); v[6] = f2bf(t1.z); v[7] = f2bf(t1.w);
            unsigned short* dst = (rr == 0 ? HBt : HB2t) + (size_t)rl * NN
                + ((size_t)blockIdx.x * 64 + nr) * N2
                + (size_t)blockIdx.y * 64 + mc8;
            *(u16x8*)dst = v;
        }
    }
}

// ---------------------------------------------------------------------------
// b2sum[c][n] = sum_bx PB2[c][bx][n]
// ---------------------------------------------------------------------------
__global__ __launch_bounds__(256) void b2fold_kernel(
    const float* __restrict__ PB2, float* __restrict__ b2sum) {
    const int r = blockIdx.x * 256 + threadIdx.x;   // c*2048 + n
    const int c = r >> 11, n = r & 2047;
    float sum = 0.f;
    #pragma unroll
    for (int bx = 0; bx < 32; bx++) sum += PB2[c * 65536 + bx * 2048 + n];
    b2sum[r] = sum;
}

// ---------------------------------------------------------------------------
// bf16 GEMM, B^T input: C[c] = A[c] @ B[c].
// 256x128 tile, BK=64, 8 waves (4Mx2N), per-wave 64x64 (4x4 frags 16x16x32).
// 3 LDS buffers (144KB), 2-tile-ahead prefetch; per K-tile:
//   vmcnt(6) [all 6 own tile-t chunks done] -> s_barrier [join: tile t
//   visible from all 8 staging waves] -> 12 ds_read (A-half0+B) -> SB(0)
//   -> 4 ds_read (A-half1) + 6 gload(tile t+2) -> lgkmcnt(4) -> 16 MFMA
//   -> lgkmcnt(0) -> 16 MFMA.
// Safety: buf (t+2)%3 == buf (t-1)%3; its readers retired reads (own
// lgkmcnt(0)) before reaching barrier(t); writers issue after barrier(t).
// Uniform 1 barrier/iter. Tail: no stage for t+2>=nt; vmcnt(0) last tile.
// MODE 0: bf16 C store + per-block partial row sums P.
// MODE 1: fp32 C store scaled by sfac[row] (final H).
// ---------------------------------------------------------------------------
#define GBM 256
#define GBN 128
#define GBK 64
#define BUF_SHORTS 24576   // 48KB per buffer

template <int MODE>
__global__ __launch_bounds__(512, 2) void gemm_bt4(
    const unsigned short* __restrict__ A, const unsigned short* __restrict__ Bt,
    void* __restrict__ Cout, float* __restrict__ P,
    const float* __restrict__ sfac) {
    __shared__ unsigned short lds[3 * BUF_SHORTS];   // 144 KB

    const int tid  = threadIdx.x;
    const int wave = tid >> 6, lane = tid & 63;
    const int wm = wave >> 1, wn = wave & 1;
    const int wr = wm * 64;             // 0,64,128,192
    const int wc = wn * 64;             // 0,64
    const int l16 = lane & 15, lhi = lane >> 4;
    const int lsw = l16 & 7;            // row-dependent swizzle bits

    const int brow = blockIdx.y * GBM;
    const int bcol = blockIdx.x * GBN;
    const size_t cz = (size_t)blockIdx.z * NN;
    const unsigned short* Ab  = A  + cz + (size_t)brow * N2;
    const unsigned short* Btb = Bt + cz + (size_t)bcol * N2;

    // 6 stage loads per thread, FIFO order = consumption order.
    // L0,L1: A rows (r&63)<32 ; L2,L3: B ; L4,L5: A rows (r&63)>=32.
    const unsigned short* src[6];
    #pragma unroll
    for (int L = 0; L < 6; L++) {
        const int g = L * 512 + tid;
        int r, s;
        const unsigned short* basep;
        if (g < 1024) {                       // A half0
            r = (g >> 8) * 64 + ((g >> 3) & 31);
            s = (g & 7) ^ (r & 7);
            basep = Ab;
        } else if (g < 2048) {                // B
            const int h = g - 1024;
            r = h >> 3;
            s = (h & 7) ^ (r & 7);
            basep = Btb;
        } else {                              // A half1
            const int h = g - 2048;
            r = (h >> 8) * 64 + 32 + ((h >> 3) & 31);
            s = (h & 7) ^ (r & 7);
            basep = Ab;
        }
        src[L] = basep + (size_t)r * N2 + s * 8;
    }

    #define STAGE6(buf, k0)                                                   \
        do {                                                                  \
            unsigned short* dst = lds + (buf) * BUF_SHORTS + tid * 8;         \
            _Pragma("unroll")                                                 \
            for (int i = 0; i < 6; i++)                                       \
                gload16(src[i] + (k0), dst + i * 4096);                       \
        } while (0)

    f32x4 acc[4][4] = {};

    // prologue: tiles 0 and 1 into bufs 0,1  (12 outstanding)
    STAGE6(0, 0);
    STAGE6(1, GBK);

    const int nt = N2 / GBK;   // 32
    for (int t = 0; t < nt; ++t) {
        const unsigned short* base = lds + (t % 3) * BUF_SHORTS;

        if (t < nt - 1) asm volatile("s_waitcnt vmcnt(6)" ::: "memory");
        else            asm volatile("s_waitcnt vmcnt(0)" ::: "memory");
        __builtin_amdgcn_s_barrier();          // tile t fully staged, all waves
        __builtin_amdgcn_sched_barrier(0);

        short8 af0[2][2], bfr[4][2], af1[2][2];
        // group 1: 12 reads (A-half0 frags + B frags)
        #pragma unroll
        for (int m = 0; m < 2; m++) {
            const unsigned short* rowp = base + wm * 2048 + (m * 16 + l16) * 64;
            #pragma unroll
            for (int ks = 0; ks < 2; ks++)
                af0[m][ks] = *(const short8*)(rowp + (((ks * 4 + lhi) ^ lsw) * 8));
        }
        #pragma unroll
        for (int n = 0; n < 4; n++) {
            const unsigned short* rowp = base + 8192 + (wc + n * 16 + l16) * 64;
            #pragma unroll
            for (int ks = 0; ks < 2; ks++)
                bfr[n][ks] = *(const short8*)(rowp + (((ks * 4 + lhi) ^ lsw) * 8));
        }
        __builtin_amdgcn_sched_barrier(0);     // group fence for lgkmcnt(4)
        // group 2: 4 reads (A-half1 frags) + prefetch tile t+2
        #pragma unroll
        for (int m = 0; m < 2; m++) {
            const unsigned short* rowp = base + 16384 + wm * 2048 + (m * 16 + l16) * 64;
            #pragma unroll
            for (int ks = 0; ks < 2; ks++)
                af1[m][ks] = *(const short8*)(rowp + (((ks * 4 + lhi) ^ lsw) * 8));
        }
        if (t + 2 < nt) STAGE6((t + 2) % 3, (t + 2) * GBK);

        asm volatile("s_waitcnt lgkmcnt(4)" ::: "memory");  // group 1 complete
        __builtin_amdgcn_sched_barrier(0);
        __builtin_amdgcn_s_setprio(1);
        #pragma unroll
        for (int ks = 0; ks < 2; ks++)
            #pragma unroll
            for (int m = 0; m < 2; m++)
                #pragma unroll
                for (int n = 0; n < 4; n++)
                    acc[m][n] = __builtin_amdgcn_mfma_f32_16x16x32_bf16(
                        af0[m][ks], bfr[n][ks], acc[m][n], 0, 0, 0);
        __builtin_amdgcn_s_setprio(0);

        asm volatile("s_waitcnt lgkmcnt(0)" ::: "memory");  // group 2 complete
        __builtin_amdgcn_sched_barrier(0);
        __builtin_amdgcn_s_setprio(1);
        #pragma unroll
        for (int ks = 0; ks < 2; ks++)
            #pragma unroll
            for (int m = 0; m < 2; m++)
                #pragma unroll
                for (int n = 0; n < 4; n++)
                    acc[2 + m][n] = __builtin_amdgcn_mfma_f32_16x16x32_bf16(
                        af1[m][ks], bfr[n][ks], acc[2 + m][n], 0, 0, 0);
        __builtin_amdgcn_s_setprio(0);
    }
    #undef STAGE6

    if constexpr (MODE == 0) {
        unsigned short* Cb = (unsigned short*)Cout + cz + (size_t)brow * N2 + bcol;
        #pragma unroll
        for (int m = 0; m < 4; m++) {
            const int r0 = wr + m * 16 + lhi * 4;
            #pragma unroll
            for (int n = 0; n < 4; n++) {
                const int c0 = wc + n * 16 + l16;
                #pragma unroll
                for (int j = 0; j < 4; j++)
                    Cb[(size_t)(r0 + j) * N2 + c0] = f2bf(acc[m][n][j]);
            }
        }
        const size_t pb = (size_t)(blockIdx.x * 2 + wn) * 4096
                        + (size_t)blockIdx.z * 2048 + brow + wr;
        #pragma unroll
        for (int m = 0; m < 4; m++)
            #pragma unroll
            for (int j = 0; j < 4; j++) {
                float ps = acc[m][0][j] + acc[m][1][j] + acc[m][2][j] + acc[m][3][j];
                ps += __shfl_xor(ps, 1);
                ps += __shfl_xor(ps, 2);
                ps += __shfl_xor(ps, 4);
                ps += __shfl_xor(ps, 8);
                if (l16 == 0) P[pb + m * 16 + lhi * 4 + j] = ps;
            }
    } else {
        float* Cb = (float*)Cout + cz + (size_t)brow * N2 + bcol;
        float sf[4][4];
        #pragma unroll
        for (int m = 0; m < 4; m++)
            #pragma unroll
            for (int j = 0; j < 4; j++)
                sf[m][j] = sfac[blockIdx.z * 2048 + brow + wr + m * 16 + lhi * 4 + j];
        #pragma unroll
        for (int m = 0; m < 4; m++) {
            const int r0 = wr + m * 16 + lhi * 4;
            #pragma unroll
            for (int n = 0; n < 4; n++) {
                const int c0 = wc + n * 16 + l16;
                #pragma unroll
                for (int j = 0; j < 4; j++)
                    Cb[(size_t)(r0 + j) * N2 + c0] = acc[m][n][j] * sf[m][j];
            }
        }
    }
}

// ---------------------------------------------------------------------------
// dinv0[r] = rsqrt(sum_cb P[cb][r])  (0 if <=0)
// ---------------------------------------------------------------------------
__global__ __launch_bounds__(256) void dinv_kernel(
    const float* __restrict__ P, float* __restrict__ dinv) {
    const int r = blockIdx.x * 256 + threadIdx.x;
    float sum = 0.f;
    #pragma unroll
    for (int cb = 0; cb < 32; cb++) sum += P[cb * 4096 + r];
    dinv[r] = sum > 0.f ? rsqrtf(sum) : 0.f;
}

// ---------------------------------------------------------------------------
// sfac[r] = dinv0[r] * rsqrt(dinv0[r] * (C0[r,:] . b2sum))   (guarded)
// ---------------------------------------------------------------------------
__device__ __forceinline__ float block_sum256(float v) {
    #pragma unroll
    for (int off = 32; off; off >>= 1) v += __shfl_xor(v, off, 64);
    __shared__ float wsum[4];
    if ((threadIdx.x & 63) == 0) wsum[threadIdx.x >> 6] = v;
    __syncthreads();
    return wsum[0] + wsum[1] + wsum[2] + wsum[3];
}

__global__ __launch_bounds__(256) void gemv_sfac_kernel(
    const unsigned short* __restrict__ C0, const float* __restrict__ b2sum,
    const float* __restrict__ dinv0, float* __restrict__ sfac) {
    const size_t r = blockIdx.x;               // 0..4095 (c*2048 + row)
    const unsigned short* row = C0 + r * N2;
    const float* bs = b2sum + ((r >> 11) << 11);
    const int base = threadIdx.x * 8;
    const u16x8 v = *(const u16x8*)&row[base];
    float sum = 0.f;
    #pragma unroll
    for (int i = 0; i < 8; i++) sum += bf2f(v[i]) * bs[base + i];
    const float tot = block_sum256(sum);
    if (threadIdx.x == 0) {
        const float d0 = dinv0[r];
        const float d1 = d0 * tot;
        sfac[r] = d0 * (d1 > 0.f ? rsqrtf(d1) : 0.f);
    }
}

// ---------------------------------------------------------------------------
// head: 64 blocks x 8 targets.
// ---------------------------------------------------------------------------
__global__ __launch_bounds__(256) void head_kernel(
    const float* __restrict__ X, const float* __restrict__ gcn_w,
    const float* __restrict__ gcn_b, const float* __restrict__ lin_w,
    const float* __restrict__ lin_b, const int* __restrict__ tx,
    float* __restrict__ y) {
    __shared__ float xr[8][512];    // 16 KB
    __shared__ float xk[8][132];    // padded
    __shared__ int trg[8];
    const int tid = threadIdx.x, b = blockIdx.x;
    if (tid < 8) trg[tid] = tx[b * 8 + tid];
    __syncthreads();
    #pragma unroll
    for (int q = 0; q < 4; q++) {
        const int idx = q * 1024 + tid * 4;
        const int t = idx >> 9, col = idx & 511;
        *(float4*)&xr[t][col] = *(const float4*)&X[(size_t)trg[t] * 512 + col];
    }
    __syncthreads();
    const int k = tid & 127, tp = tid >> 7;
    const float* wrp = gcn_w + (size_t)k * 512;
    float d[4] = {0.f, 0.f, 0.f, 0.f};
    for (int i = 0; i < 512; i += 4) {
        const float4 wv = *(const float4*)&wrp[i];
        #pragma unroll
        for (int tt = 0; tt < 4; tt++) {
            const float* xp = xr[tp * 4 + tt];
            d[tt] += xp[i] * wv.x + xp[i+1] * wv.y + xp[i+2] * wv.z + xp[i+3] * wv.w;
        }
    }
    const float gb = gcn_b[k];
    #pragma unroll
    for (int tt = 0; tt < 4; tt++) xk[tp * 4 + tt][k] = fmaxf(d[tt] + gb, 0.f);
    __syncthreads();
    if (tid < 64) {
        const int t = tid >> 3, o = tid & 7;
        float a = lin_b[o];
        const float* lw = lin_w + o * 256;
        for (int kk = 0; kk < 128; kk++)
            a += xk[t][kk] * (lw[kk] + lw[128 + kk]);
        y[(size_t)(b * 8 + t) * 8 + o] = a;
    }
}

__global__ void wsoft_kernel(const float* __restrict__ w01,
                             const float* __restrict__ w02,
                             const float* __restrict__ w11,
                             float* __restrict__ out) {
    const int tid = threadIdx.x;
    if (tid < 6) {
        const int wi = tid >> 1, c = tid & 1;
        const float* w = (wi == 0 ? w01 : (wi == 1 ? w02 : w11)) + c * 5;
        float mx = w[0];
        for (int e = 1; e < 5; e++) mx = fmaxf(mx, w[e]);
        float ex[5], sum = 0.f;
        for (int e = 0; e < 5; e++) { ex[e] = expf(w[e] - mx); sum += ex[e]; }
        for (int e = 0; e < 5; e++) out[tid * 5 + e] = ex[e] / sum;
    }
}

// ---------------------------------------------------------------------------
extern "C" void kernel_launch(void* const* d_in, const int* in_sizes, int n_in,
                              void* d_out, int out_size, void* d_ws, size_t ws_size,
                              hipStream_t stream) {
    const float* A     = (const float*)d_in[0];
    const float* X     = (const float*)d_in[1];
    const float* w01   = (const float*)d_in[2];
    const float* w02   = (const float*)d_in[3];
    const float* w11   = (const float*)d_in[4];
    const float* gcn_w = (const float*)d_in[5];
    const float* gcn_b = (const float*)d_in[6];
    const float* lin_w = (const float*)d_in[7];
    const float* lin_b = (const float*)d_in[8];
    const int*   tx    = (const int*)d_in[9];

    float* out  = (float*)d_out;
    float* y    = out;                 // [512, 8]
    float* allw = out + 4096;          // [3, 2, 5]
    float* H    = out + 4126;          // [2, 2048, 2048] fp32 final output

    unsigned short* HA   = (unsigned short*)d_ws;       // [2,N,N] bf16
    unsigned short* HBt  = HA + 2 * NN;                 // [2,N,N] bf16 (B^T)
    unsigned short* HB2t = HBt + 2 * NN;                // [2,N,N] bf16 (B^T)
    unsigned short* C0   = HB2t + 2 * NN;               // [2,N,N] bf16 layer-0 product
    float* P     = (float*)(C0 + 2 * NN);               // [32][4096] partials
    float* PB2   = P + 32 * 4096;                       // [2][32][2048]
    float* dinv0 = PB2 + 2 * 32 * 2048;                 // [4096]
    float* b2sum = dinv0 + 4096;                        // [4096]
    float* sfac  = b2sum + 4096;                        // [4096]

    combine_kernel<<<dim3(32, 32), 512, 0, stream>>>(A, w01, w02, w11,
                                                     HA, HBt, HB2t, PB2);
    b2fold_kernel<<<16, 256, 0, stream>>>(PB2, b2sum);
    gemm_bt4<0><<<dim3(16, 8, 2), 512, 0, stream>>>(HA, HBt, C0, P, nullptr);
    dinv_kernel<<<16, 256, 0, stream>>>(P, dinv0);
    gemv_sfac_kernel<<<4096, 256, 0, stream>>>(C0, b2sum, dinv0, sfac);
    gemm_bt4<1><<<dim3(16, 8, 2), 512, 0, stream>>>(C0, HB2t, H, nullptr, sfac);
    head_kernel<<<64, 256, 0, stream>>>(X, gcn_w, gcn_b, lin_w, lin_b, tx, y);
    wsoft_kernel<<<1, 64, 0, stream>>>(w01, w02, w11, allw);
}